// Round 7
// baseline (186.728 us; speedup 1.0000x reference)
//
#include <hip/hip_runtime.h>
#include <hip/hip_bf16.h>

// Linear layer: out[M,N] = x[M,K] @ W[N,K]^T + b[N], fp32 in/out.
// M=32768, N=512, K=512.
// R7: BARRIER-FREE K-loop. W-slab (64 rows x full K=512, bf16 = 65KB)
// staged to LDS once; A fragments read directly from global (per-lane
// K-contiguous rows == MFMA A layout; paired dwordx4 covers full 128B
// lines) with a distance-2 register pipeline. No s_barrier in the loop
// -> compiler emits partial vmcnt waits -> ~2 iterations of load flight.
// Tile 256Mx64N, 4 waves of 64x64. LDS 65KB -> 2 blocks/CU = 8
// independent waves/CU. XCD swizzle: 8 n-blocks of an m-slab adjacent on
// one XCD (A served from its L2); W (1MB) is L2-resident everywhere.

#define M_DIM 32768
#define N_DIM 512
#define K_DIM 512
#define BK 32
#define LDWS 520  // W LDS row stride (bf16): 260 dwords -> balanced banks for b128

typedef __bf16 bf16x8 __attribute__((ext_vector_type(8)));
typedef __bf16 bf16x4 __attribute__((ext_vector_type(4)));
typedef float floatx4 __attribute__((ext_vector_type(4)));

__global__ __launch_bounds__(256, 2) void linear_nobar(
    const float* __restrict__ A,    // [M, K]
    const float* __restrict__ W,    // [N, K]
    const float* __restrict__ bias, // [N]
    float* __restrict__ C)          // [M, N]
{
    __shared__ __bf16 sW[64 * LDWS];  // 66,560 B

    const int t = threadIdx.x;
    const int wave = t >> 6;
    const int lane = t & 63;
    const int l16 = lane & 15;
    const int kh = lane >> 4;

    // XCD swizzle: bid = slot*8 + xcd; slot: nT fastest -> the 8 n-blocks
    // sharing an A-slab are adjacent slots on ONE XCD.
    const int bid = blockIdx.x;
    const int xcd = bid & 7;
    const int slot = bid >> 3;            // 0..127
    const int nT = slot & 7;              // N/64 = 8
    const int mT = xcd * 16 + (slot >> 3);// M/256 = 128
    const int mBase = mT * 256 + wave * 64;
    const int nBase = nT * 64;

    // ---- A direct-frag pointers + distance-2 prefetch (issue FIRST) ----
    const float* aP[4];
#pragma unroll
    for (int i = 0; i < 4; ++i)
        aP[i] = A + (size_t)(mBase + i * 16 + l16) * K_DIM + kh * 8;

    floatx4 pa[2][4][2];
#pragma unroll
    for (int i = 0; i < 4; ++i) {
        pa[0][i][0] = *(const floatx4*)(aP[i]);
        pa[0][i][1] = *(const floatx4*)(aP[i] + 4);
        pa[1][i][0] = *(const floatx4*)(aP[i] + BK);
        pa[1][i][1] = *(const floatx4*)(aP[i] + BK + 4);
    }

    // ---- W staging: 64 rows x 512 fp32 -> bf16 LDS (ONE TIME) ----
    {
        const int r = t >> 2;             // 0..63
        const int c0 = (t & 3) * 4;       // 0,4,8,12
        const float* wrow = W + (size_t)(nBase + r) * K_DIM;
#pragma unroll 8
        for (int j = 0; j < 32; ++j) {
            floatx4 wv = *(const floatx4*)(wrow + c0 + j * 16);
            bf16x4 wb;
#pragma unroll
            for (int q = 0; q < 4; ++q) wb[q] = (__bf16)wv[q];
            *(bf16x4*)&sW[r * LDWS + c0 + j * 16] = wb;
        }
    }
    __syncthreads();  // the ONLY barrier in the kernel

    floatx4 acc[4][4];
#pragma unroll
    for (int i = 0; i < 4; ++i)
#pragma unroll
        for (int j = 0; j < 4; ++j)
            acc[i][j] = (floatx4)0.f;

#define STEP(s, kt)                                                           \
    {                                                                         \
        bf16x8 aF[4];                                                         \
        _Pragma("unroll") for (int i = 0; i < 4; ++i) {                       \
            _Pragma("unroll") for (int j = 0; j < 4; ++j) {                   \
                aF[i][j]     = (__bf16)pa[s][i][0][j];                        \
                aF[i][4 + j] = (__bf16)pa[s][i][1][j];                        \
            }                                                                 \
        }                                                                     \
        if ((kt) + 2 * BK < K_DIM) { /* reissue into freed set: dist 2 */     \
            _Pragma("unroll") for (int i = 0; i < 4; ++i) {                   \
                pa[s][i][0] = *(const floatx4*)(aP[i] + (kt) + 2 * BK);       \
                pa[s][i][1] = *(const floatx4*)(aP[i] + (kt) + 2 * BK + 4);   \
            }                                                                 \
        }                                                                     \
        bf16x8 wF[4];                                                         \
        _Pragma("unroll") for (int ni = 0; ni < 4; ++ni)                      \
            wF[ni] = *(const bf16x8*)&sW[(ni * 16 + l16) * LDWS +             \
                                         kh * 8 + (kt)];                      \
        _Pragma("unroll") for (int mi = 0; mi < 4; ++mi)                      \
            _Pragma("unroll") for (int ni = 0; ni < 4; ++ni)                  \
                acc[mi][ni] = __builtin_amdgcn_mfma_f32_16x16x32_bf16(        \
                    aF[mi], wF[ni], acc[mi][ni], 0, 0, 0);                    \
    }

    for (int it = 0; it < K_DIM / (2 * BK); ++it) {
        const int kt = it * 2 * BK;
        STEP(0, kt);
        STEP(1, kt + BK);
    }
#undef STEP

    // Epilogue: D mapping col = lane&15, row = (lane>>4)*4 + reg (verified).
#pragma unroll
    for (int ni = 0; ni < 4; ++ni) {
        const int gcol = nBase + ni * 16 + l16;
        const float bv = bias[gcol];
#pragma unroll
        for (int mi = 0; mi < 4; ++mi) {
            const int rowBase = mBase + mi * 16 + kh * 4;
#pragma unroll
            for (int r = 0; r < 4; ++r)
                C[(size_t)(rowBase + r) * N_DIM + gcol] = acc[mi][ni][r] + bv;
        }
    }
}

extern "C" void kernel_launch(void* const* d_in, const int* in_sizes, int n_in,
                              void* d_out, int out_size, void* d_ws, size_t ws_size,
                              hipStream_t stream) {
    const float* x = (const float*)d_in[0];
    const float* w = (const float*)d_in[1];
    const float* b = (const float*)d_in[2];
    float* out = (float*)d_out;

    dim3 grid((M_DIM / 256) * (N_DIM / 64));  // 1024 blocks, 1D for swizzle
    dim3 block(256);
    linear_nobar<<<grid, block, 0, stream>>>(x, w, b, out);
}